// Round 3
// baseline (355.975 us; speedup 1.0000x reference)
//
#include <hip/hip_runtime.h>

#define LN_EPS 1e-5f

typedef short bf16x8 __attribute__((ext_vector_type(8)));
typedef float f32x4  __attribute__((ext_vector_type(4)));

__device__ __forceinline__ unsigned short f2bf(float f) {
  unsigned u = __float_as_uint(f);
  u += 0x7fffu + ((u >> 16) & 1u);          // RNE
  return (unsigned short)(u >> 16);
}
__device__ __forceinline__ float bf2f(unsigned short s) {
  return __uint_as_float(((unsigned)s) << 16);
}

__device__ __forceinline__ bf16x8 pack8(float4 a, float4 b) {
  bf16x8 v;
  v[0] = (short)f2bf(a.x); v[1] = (short)f2bf(a.y);
  v[2] = (short)f2bf(a.z); v[3] = (short)f2bf(a.w);
  v[4] = (short)f2bf(b.x); v[5] = (short)f2bf(b.y);
  v[6] = (short)f2bf(b.z); v[7] = (short)f2bf(b.w);
  return v;
}

// ---------------------------------------------------------------------------
// Prep (same algebra as v2): BT = bf16 granule image of
//   chunks  0..15 : CW = codebook @ W_in          (512 codes x 256 d)
//   chunks 16..23 : G  = W_in^T @ W_in            (256 x 256, symmetric)
// plus c2 = |c|^2, code_out = CB @ W_out^T, loss/ticket zero.
// LDS stride bumped 260 -> 268 (4-way instead of 8-way bank conflict on the
// per-lane As[c][d] b128 reads; 268 words keeps 16-B row alignment).
// ---------------------------------------------------------------------------
__global__ __launch_bounds__(256) void prep_kernel(
    const float* __restrict__ codebook, const float* __restrict__ W_in,
    const float* __restrict__ W_out,
    float* __restrict__ loss_acc, unsigned* __restrict__ ticket,
    float* __restrict__ c2, float* __restrict__ code_out,
    unsigned short* __restrict__ BT) {
  const int b = blockIdx.x, t = threadIdx.x;
  __shared__ float As[32][268];
  __shared__ float Bs[16][268];
  __shared__ float Res[32][17];

  if (b < 64) {
    if (b == 0 && t == 0) { *loss_acc = 0.f; *ticket = 0u; }
    int code = b * 8 + (t >> 5);
    const float* src = codebook + (size_t)code * 256 + (t & 31) * 8;
    float4 x0 = *(const float4*)src, x1 = *(const float4*)(src + 4);
    float s = x0.x * x0.x + x0.y * x0.y + x0.z * x0.z + x0.w * x0.w +
              x1.x * x1.x + x1.y * x1.y + x1.z * x1.z + x1.w * x1.w;
    s += __shfl_xor(s, 1);  s += __shfl_xor(s, 2);
    s += __shfl_xor(s, 4);  s += __shfl_xor(s, 8);
    s += __shfl_xor(s, 16);
    if ((t & 31) == 0) c2[code] = s;
    return;
  }

  if (b < 320) {
    // ---- code_out = CB @ W_out^T : tile 32 codes x 16 e ----
    int bi = b - 64, ci = bi & 15, ei = bi >> 4;
    {
      int row = t >> 4, col = (t & 15) * 16;
      const float4* s = (const float4*)(W_out + (size_t)(ei * 16 + row) * 256 + col);
      float4* d = (float4*)&Bs[row][col];
      d[0] = s[0]; d[1] = s[1]; d[2] = s[2]; d[3] = s[3];
    }
    {
      int row = t >> 3, col = (t & 7) * 32;
      const float4* s = (const float4*)(codebook + (size_t)(ci * 32 + row) * 256 + col);
      float4* d = (float4*)&As[row][col];
      #pragma unroll
      for (int k = 0; k < 8; k++) d[k] = s[k];
    }
    __syncthreads();
    int c = t & 31, e0 = t >> 5;
    float a0 = 0.f, a1 = 0.f;
    #pragma unroll 4
    for (int d = 0; d < 256; d += 4) {
      float4 cv = *(const float4*)&As[c][d];
      float4 w0 = *(const float4*)&Bs[e0][d];
      float4 w1 = *(const float4*)&Bs[e0 + 8][d];
      a0 += cv.x * w0.x + cv.y * w0.y + cv.z * w0.z + cv.w * w0.w;
      a1 += cv.x * w1.x + cv.y * w1.y + cv.z * w1.z + cv.w * w1.w;
    }
    code_out[(size_t)(ci * 32 + c) * 256 + ei * 16 + e0]     = a0;
    code_out[(size_t)(ci * 32 + c) * 256 + ei * 16 + e0 + 8] = a1;
    return;
  }

  if (b < 576) {
    // ---- CW = CB @ W_in : tile 32 codes x 16 d ----
    int bi = b - 320, ci = bi & 15, di = bi >> 4;
    int c0 = ci * 32, d0 = di * 16;
    {
      int e = t;
      const float* src = W_in + (size_t)e * 256 + d0;
      #pragma unroll
      for (int k = 0; k < 4; k++) {
        float4 v = *(const float4*)(src + k * 4);
        Bs[k * 4 + 0][e] = v.x; Bs[k * 4 + 1][e] = v.y;
        Bs[k * 4 + 2][e] = v.z; Bs[k * 4 + 3][e] = v.w;
      }
    }
    {
      int row = t >> 3, col = (t & 7) * 32;
      const float4* s = (const float4*)(codebook + (size_t)(c0 + row) * 256 + col);
      float4* d = (float4*)&As[row][col];
      #pragma unroll
      for (int k = 0; k < 8; k++) d[k] = s[k];
    }
    __syncthreads();
    int c = t & 31, dl = t >> 5;
    float a0 = 0.f, a1 = 0.f;
    #pragma unroll 4
    for (int d = 0; d < 256; d += 4) {
      float4 cv = *(const float4*)&As[c][d];
      float4 w0 = *(const float4*)&Bs[dl][d];
      float4 w1 = *(const float4*)&Bs[dl + 8][d];
      a0 += cv.x * w0.x + cv.y * w0.y + cv.z * w0.z + cv.w * w0.w;
      a1 += cv.x * w1.x + cv.y * w1.y + cv.z * w1.z + cv.w * w1.w;
    }
    Res[c][dl] = a0; Res[c][dl + 8] = a1;
    __syncthreads();
    if (t < 64) {
      int c2i = t & 31, kqo = t >> 5;          // kqo in {0,1}
      int code = c0 + c2i, dg = d0 + kqo * 8;
      int cl = code & 255;
      int chunk = (code >> 8) * 8 + (dg >> 5);
      int kq = (dg >> 3) & 3;
      float4 x0, x1;
      x0.x = Res[c2i][kqo * 8 + 0]; x0.y = Res[c2i][kqo * 8 + 1];
      x0.z = Res[c2i][kqo * 8 + 2]; x0.w = Res[c2i][kqo * 8 + 3];
      x1.x = Res[c2i][kqo * 8 + 4]; x1.y = Res[c2i][kqo * 8 + 5];
      x1.z = Res[c2i][kqo * 8 + 6]; x1.w = Res[c2i][kqo * 8 + 7];
      *(bf16x8*)(BT + chunk * 8192 + (cl >> 4) * 512 + kq * 128 + (cl & 15) * 8) =
          pack8(x0, x1);
    }
    return;
  }

  {
    // ---- G = W_in^T W_in ----
    int bi = b - 576;                 // 0..127
    int ks = bi & 7, bt = bi >> 3;
    int a0c = ks * 32, b0c = bt * 16;
    {
      int e = t;
      const float* srca = W_in + (size_t)e * 256 + a0c;
      #pragma unroll
      for (int k = 0; k < 8; k++) {
        float4 v = *(const float4*)(srca + k * 4);
        As[k * 4 + 0][e] = v.x; As[k * 4 + 1][e] = v.y;
        As[k * 4 + 2][e] = v.z; As[k * 4 + 3][e] = v.w;
      }
      const float* srcb = W_in + (size_t)e * 256 + b0c;
      #pragma unroll
      for (int k = 0; k < 4; k++) {
        float4 v = *(const float4*)(srcb + k * 4);
        Bs[k * 4 + 0][e] = v.x; Bs[k * 4 + 1][e] = v.y;
        Bs[k * 4 + 2][e] = v.z; Bs[k * 4 + 3][e] = v.w;
      }
    }
    __syncthreads();
    int al = t & 31, bl = t >> 5;
    float s0 = 0.f, s1 = 0.f;
    #pragma unroll 4
    for (int d = 0; d < 256; d += 4) {
      float4 av = *(const float4*)&As[al][d];
      float4 w0 = *(const float4*)&Bs[bl][d];
      float4 w1 = *(const float4*)&Bs[bl + 8][d];
      s0 += av.x * w0.x + av.y * w0.y + av.z * w0.z + av.w * w0.w;
      s1 += av.x * w1.x + av.y * w1.y + av.z * w1.z + av.w * w1.w;
    }
    Res[al][bl] = s0; Res[al][bl + 8] = s1;
    __syncthreads();
    if (t < 64) {
      int bcol = t & 15, kqo = t >> 4;   // kqo 0..3
      int cl = b0c + bcol;
      int chunk = 16 + ks;
      float4 x0, x1;
      x0.x = Res[kqo * 8 + 0][bcol]; x0.y = Res[kqo * 8 + 1][bcol];
      x0.z = Res[kqo * 8 + 2][bcol]; x0.w = Res[kqo * 8 + 3][bcol];
      x1.x = Res[kqo * 8 + 4][bcol]; x1.y = Res[kqo * 8 + 5][bcol];
      x1.z = Res[kqo * 8 + 6][bcol]; x1.w = Res[kqo * 8 + 7][bcol];
      *(bf16x8*)(BT + chunk * 8192 + (cl >> 4) * 512 + kqo * 128 + (cl & 15) * 8) =
          pack8(x0, x1);
    }
  }
}

// ---------------------------------------------------------------------------
// Main v3: 4 fat waves (256 threads), 64 rows/block, wave owns 64 codes.
//  - A-frags shared work: LDS GEMM reads per block 1152 -> 768
//  - phase-3 LN: 8-lanes-per-row, 6 shuffles per 8 rows (was 96)
//  - loss atomic/fence/ticket moved after the stores (off critical path)
// ---------------------------------------------------------------------------
__global__ __launch_bounds__(256, 4) void main_kernel(
    const float* __restrict__ hidden, const int* __restrict__ mask,
    const float* __restrict__ gamma, const float* __restrict__ beta,
    const float* __restrict__ c2g, const float* __restrict__ code_out,
    const unsigned short* __restrict__ BT,
    float* __restrict__ loss_acc, unsigned* __restrict__ ticket,
    float* __restrict__ out) {

  __shared__ unsigned short H[64 * 264];    // bf16 H tile, stride 264
  __shared__ unsigned sminp[256];
  __shared__ float    lossw[4];
  __shared__ int      ridx[64];

  const int t    = threadIdx.x;             // 0..255
  const int lane = t & 63;
  const int w    = t >> 6;                  // wave 0..3
  const int l15  = lane & 15;
  const int quad = lane >> 4;
  const int row0 = blockIdx.x * 64;

  // ---- stage H: contiguous global reads, b128 LDS writes ----
  #pragma unroll
  for (int i = 0; i < 8; i++) {
    int flat = t * 8 + i * 2048;
    int r = flat >> 8, c = flat & 255;
    const float* src = hidden + (size_t)row0 * 256 + flat;
    float4 x0 = *(const float4*)src, x1 = *(const float4*)(src + 4);
    *(bf16x8*)(H + r * 264 + c) = pack8(x0, x1);
  }
  __syncthreads();   // B1: H visible

  // b-frag base: chunk*8192 + (w*4+j)*512 + quad*128 + l15*8
  const unsigned short* BTw = BT + w * 2048 + lane * 8;
  const f32x4 zf = {0.f, 0.f, 0.f, 0.f};

  unsigned runp[16];
  #pragma unroll
  for (int r = 0; r < 16; r++) runp[r] = 0xFFFFFFFFu;

  f32x4 acc[4][4];

  // ---------------- score passes: S = H * CW^T ----------------
  #pragma unroll
  for (int pass = 0; pass < 2; pass++) {
    #pragma unroll
    for (int i = 0; i < 4; i++)
      #pragma unroll
      for (int j = 0; j < 4; j++) acc[i][j] = zf;

    #pragma unroll 2
    for (int ks = 0; ks < 8; ks++) {
      const unsigned short* bp = BTw + (pass * 8 + ks) * 8192;
      bf16x8 a[4];
      #pragma unroll
      for (int i = 0; i < 4; i++)
        a[i] = *(const bf16x8*)(H + (i * 16 + l15) * 264 + ks * 32 + quad * 8);
      #pragma unroll
      for (int j = 0; j < 4; j++) {
        bf16x8 bj = *(const bf16x8*)(bp + j * 512);
        #pragma unroll
        for (int i = 0; i < 4; i++)
          acc[i][j] = __builtin_amdgcn_mfma_f32_16x16x32_bf16(a[i], bj, acc[i][j], 0, 0, 0);
      }
    }
    // fold: m = |c|^2 - 2 h.cw ; pack sortable (dist | 9-bit code); running min
    #pragma unroll
    for (int j = 0; j < 4; j++) {
      int code = pass * 256 + w * 64 + j * 16 + l15;
      float cc = c2g[code];
      #pragma unroll
      for (int i = 0; i < 4; i++)
        #pragma unroll
        for (int r = 0; r < 4; r++) {
          float m = cc - 2.f * acc[i][j][r];
          unsigned bits = __float_as_uint(m);
          unsigned u = bits ^ (0x80000000u | (unsigned)((int)bits >> 31));
          unsigned p = (u & 0xFFFFFE00u) | (unsigned)code;
          int ri = i * 4 + r;
          runp[ri] = min(runp[ri], p);
        }
    }
  }

  // reduce argmin across the 16 l15-lanes of each quad group
  #pragma unroll
  for (int ri = 0; ri < 16; ri++) {
    unsigned v = runp[ri];
    v = min(v, (unsigned)__shfl_xor((int)v, 1));
    v = min(v, (unsigned)__shfl_xor((int)v, 2));
    v = min(v, (unsigned)__shfl_xor((int)v, 4));
    v = min(v, (unsigned)__shfl_xor((int)v, 8));
    if (l15 == 0) {
      int i = ri >> 2, r = ri & 3;
      sminp[w * 64 + (i * 16 + quad * 4 + r)] = v;
    }
  }

  // ---------------- Gram pass: Y^T = G * H^T  (G symmetric) ----------------
  #pragma unroll
  for (int i = 0; i < 4; i++)
    #pragma unroll
    for (int j = 0; j < 4; j++) acc[i][j] = zf;

  #pragma unroll 2
  for (int ks = 0; ks < 8; ks++) {
    const unsigned short* gp = BTw + (16 + ks) * 8192;
    bf16x8 a[4];
    #pragma unroll
    for (int i = 0; i < 4; i++)
      a[i] = *(const bf16x8*)(H + (i * 16 + l15) * 264 + ks * 32 + quad * 8);
    #pragma unroll
    for (int j = 0; j < 4; j++) {
      bf16x8 gj = *(const bf16x8*)(gp + j * 512);
      #pragma unroll
      for (int i = 0; i < 4; i++)
        acc[i][j] = __builtin_amdgcn_mfma_f32_16x16x32_bf16(gj, a[i], acc[i][j], 0, 0, 0);
    }
  }
  // lane holds Y[hrow = i*16+l15][d' = w*64+j*16+quad*4+reg] -> dot with H
  {
    float lsum = 0.f;
    #pragma unroll
    for (int i = 0; i < 4; i++)
      #pragma unroll
      for (int j = 0; j < 4; j++) {
        const unsigned short* hp =
            H + (i * 16 + l15) * 264 + w * 64 + j * 16 + quad * 4;
        uint2 hv = *(const uint2*)hp;
        lsum += acc[i][j][0] * bf2f((unsigned short)(hv.x & 0xFFFFu));
        lsum += acc[i][j][1] * bf2f((unsigned short)(hv.x >> 16));
        lsum += acc[i][j][2] * bf2f((unsigned short)(hv.y & 0xFFFFu));
        lsum += acc[i][j][3] * bf2f((unsigned short)(hv.y >> 16));
      }
    #pragma unroll
    for (int m = 1; m < 64; m <<= 1) lsum += __shfl_xor(lsum, m);
    if (lane == 0) lossw[w] = lsum;
  }
  __syncthreads();   // B2: sminp + lossw visible

  unsigned bv = 0xFFFFFFFFu;
  if (t < 64) {      // merge 4 waves, publish idx (dist deferred)
    bv = sminp[t];
    #pragma unroll
    for (int ww = 1; ww < 4; ww++) bv = min(bv, sminp[ww * 64 + t]);
    ridx[t] = (int)(bv & 511u);
  }
  __syncthreads();   // B3: ridx visible

  // ---- phase 3: h = hidden + mask*code_out[idx]; LayerNorm; store ----
  // 8 lanes per row: row = w*16 + rr*8 + (lane>>3), cols (lane&7)*32..+31
  {
    const int rowg = lane >> 3;
    const int part = lane & 7;
    #pragma unroll
    for (int rr = 0; rr < 2; rr++) {
      int row = w * 16 + rr * 8 + rowg;
      int gr  = row0 + row;
      float mf = mask[gr] ? 1.f : 0.f;
      int code = ridx[row];
      const float* hsrc = hidden   + (size_t)gr * 256 + part * 32;
      const float* osrc = code_out + (size_t)code * 256 + part * 32;
      float s = 0.f, sq = 0.f;
      #pragma unroll
      for (int k = 0; k < 8; k++) {
        float4 h4 = *(const float4*)(hsrc + k * 4);
        float4 o4 = *(const float4*)(osrc + k * 4);
        float a0 = h4.x + mf * o4.x, a1 = h4.y + mf * o4.y;
        float a2 = h4.z + mf * o4.z, a3 = h4.w + mf * o4.w;
        s  += (a0 + a1) + (a2 + a3);
        sq += (a0 * a0 + a1 * a1) + (a2 * a2 + a3 * a3);
      }
      s += __shfl_xor(s, 1);  sq += __shfl_xor(sq, 1);
      s += __shfl_xor(s, 2);  sq += __shfl_xor(sq, 2);
      s += __shfl_xor(s, 4);  sq += __shfl_xor(sq, 4);
      float mean = s * (1.f / 256.f);
      float var  = sq * (1.f / 256.f) - mean * mean;
      float rstd = rsqrtf(var + LN_EPS);
      float* dst = out + (size_t)gr * 256 + part * 32;
      const float* gsrc = gamma + part * 32;
      const float* bsrc = beta  + part * 32;
      #pragma unroll
      for (int k = 0; k < 8; k++) {
        float4 h4 = *(const float4*)(hsrc + k * 4);
        float4 o4 = *(const float4*)(osrc + k * 4);
        float4 g4 = *(const float4*)(gsrc + k * 4);
        float4 b4 = *(const float4*)(bsrc + k * 4);
        float4 res;
        res.x = (h4.x + mf * o4.x - mean) * rstd * g4.x + b4.x;
        res.y = (h4.y + mf * o4.y - mean) * rstd * g4.y + b4.y;
        res.z = (h4.z + mf * o4.z - mean) * rstd * g4.z + b4.z;
        res.w = (h4.w + mf * o4.w - mean) * rstd * g4.w + b4.w;
        *(float4*)(dst + k * 4) = res;
      }
    }
  }

  // ---- deferred loss finalize (off the phase-3 critical path) ----
  if (t < 64) {
    unsigned u = bv & 0xFFFFFE00u;
    unsigned bits = (u & 0x80000000u) ? (u ^ 0x80000000u) : ~u;
    float dist = __uint_as_float(bits);
    #pragma unroll
    for (int m = 1; m < 64; m <<= 1) dist += __shfl_xor(dist, m);
    if (t == 0) {
      float lw = lossw[0] + lossw[1] + lossw[2] + lossw[3];
      atomicAdd(loss_acc, dist + lw);
      __threadfence();
      unsigned done = atomicAdd(ticket, 1u);
      if (done == gridDim.x - 1) {
        float total = atomicAdd(loss_acc, 0.f);
        out[16777216] = 1.25f * total * (1.f / 16777216.f);
      }
    }
  }
}

extern "C" void kernel_launch(void* const* d_in, const int* in_sizes, int n_in,
                              void* d_out, int out_size, void* d_ws, size_t ws_size,
                              hipStream_t stream) {
  (void)in_sizes; (void)n_in; (void)out_size; (void)ws_size;
  const float* hidden   = (const float*)d_in[0];
  const int*   mask     = (const int*)d_in[1];
  const float* codebook = (const float*)d_in[2];
  const float* W_in     = (const float*)d_in[3];
  const float* W_out    = (const float*)d_in[4];
  const float* gamma    = (const float*)d_in[5];
  const float* beta     = (const float*)d_in[6];
  float* out = (float*)d_out;

  float* wsf      = (float*)d_ws;
  float* loss_acc = wsf;                        // [1]
  unsigned* ticket = (unsigned*)(wsf + 1);      // [1]
  float* c2       = wsf + 64;                   // [512]
  float* code_out = wsf + 64 + 512;             // [512*256]
  unsigned short* BT = (unsigned short*)(wsf + 64 + 512 + 512 * 256); // 24*8192 bf16

  prep_kernel<<<704, 256, 0, stream>>>(codebook, W_in, W_out, loss_acc, ticket,
                                       c2, code_out, BT);
  main_kernel<<<1024, 256, 0, stream>>>(hidden, mask, gamma, beta, c2, code_out,
                                        BT, loss_acc, ticket, out);
}

// Round 6
// 185.345 us; speedup vs baseline: 1.9206x; 1.9206x over previous
//
#include <hip/hip_runtime.h>

#define LN_EPS 1e-5f

typedef short bf16x8 __attribute__((ext_vector_type(8)));
typedef float f32x4  __attribute__((ext_vector_type(4)));

__device__ __forceinline__ unsigned short f2bf(float f) {
  unsigned u = __float_as_uint(f);
  u += 0x7fffu + ((u >> 16) & 1u);          // RNE
  return (unsigned short)(u >> 16);
}
__device__ __forceinline__ float bf2f(unsigned short s) {
  return __uint_as_float(((unsigned)s) << 16);
}

__device__ __forceinline__ bf16x8 pack8(float4 a, float4 b) {
  bf16x8 v;
  v[0] = (short)f2bf(a.x); v[1] = (short)f2bf(a.y);
  v[2] = (short)f2bf(a.z); v[3] = (short)f2bf(a.w);
  v[4] = (short)f2bf(b.x); v[5] = (short)f2bf(b.y);
  v[6] = (short)f2bf(b.z); v[7] = (short)f2bf(b.w);
  return v;
}

// ---------------------------------------------------------------------------
// Prep (byte-identical to round 3): BT = pre-tiled bf16 image of
// [W_in: chunks 0..7 | CB: chunks 8..23], c2, code_out = CB@W_out^T,
// loss/ticket zero.
// ---------------------------------------------------------------------------
__global__ __launch_bounds__(256) void prep_kernel(
    const float* __restrict__ codebook, const float* __restrict__ W_in,
    const float* __restrict__ W_out,
    float* __restrict__ loss_acc, unsigned* __restrict__ ticket,
    float* __restrict__ c2, float* __restrict__ code_out,
    unsigned short* __restrict__ BT) {
  const int b = blockIdx.x, t = threadIdx.x;
  if (b < 32) {
    if (b == 0 && t == 0) { *loss_acc = 0.f; *ticket = 0u; }
    int e = b * 8 + (t >> 5);
    int c32 = t & 31, ks = c32 >> 2, kq = c32 & 3;
    const float* src = W_in + e * 256 + c32 * 8;
    float4 x0 = *(const float4*)src, x1 = *(const float4*)(src + 4);
    *(bf16x8*)(BT + ks * 8192 + (e >> 6) * 2048 + ((e >> 4) & 3) * 512 +
               kq * 128 + (e & 15) * 8) = pack8(x0, x1);
  } else if (b < 96) {
    int code = (b - 32) * 8 + (t >> 5);
    int c32 = t & 31, ks = c32 >> 2, kq = c32 & 3;
    const float* src = codebook + code * 256 + c32 * 8;
    float4 x0 = *(const float4*)src, x1 = *(const float4*)(src + 4);
    int cl = code & 255;
    int chunk = 8 + (code >> 8) * 8 + ks;
    *(bf16x8*)(BT + chunk * 8192 + (cl >> 6) * 2048 + ((cl >> 4) & 3) * 512 +
               kq * 128 + (cl & 15) * 8) = pack8(x0, x1);
    float s = x0.x * x0.x + x0.y * x0.y + x0.z * x0.z + x0.w * x0.w +
              x1.x * x1.x + x1.y * x1.y + x1.z * x1.z + x1.w * x1.w;
    s += __shfl_xor(s, 1);  s += __shfl_xor(s, 2);
    s += __shfl_xor(s, 4);  s += __shfl_xor(s, 8);
    s += __shfl_xor(s, 16);
    if ((t & 31) == 0) c2[code] = s;
  } else {
    __shared__ float Cs[32][260];
    __shared__ float Ws[16][260];
    int bi = b - 96, ci = bi & 15, ei = bi >> 4;
    {
      int row = t >> 4, col = (t & 15) * 16;
      const float4* s = (const float4*)(W_out + (size_t)(ei * 16 + row) * 256 + col);
      float4* d = (float4*)&Ws[row][col];
      d[0] = s[0]; d[1] = s[1]; d[2] = s[2]; d[3] = s[3];
    }
    {
      int row = t >> 3, col = (t & 7) * 32;
      const float4* s = (const float4*)(codebook + (size_t)(ci * 32 + row) * 256 + col);
      float4* d = (float4*)&Cs[row][col];
      #pragma unroll
      for (int k = 0; k < 8; k++) d[k] = s[k];
    }
    __syncthreads();
    int c = t & 31, e0 = t >> 5;
    float a0 = 0.f, a1 = 0.f;
    #pragma unroll 4
    for (int d = 0; d < 256; d += 4) {
      float4 cv = *(const float4*)&Cs[c][d];
      float4 w0 = *(const float4*)&Ws[e0][d];
      float4 w1 = *(const float4*)&Ws[e0 + 8][d];
      a0 += cv.x * w0.x + cv.y * w0.y + cv.z * w0.z + cv.w * w0.w;
      a1 += cv.x * w1.x + cv.y * w1.y + cv.z * w1.z + cv.w * w1.w;
    }
    code_out[(size_t)(ci * 32 + c) * 256 + ei * 16 + e0]     = a0;
    code_out[(size_t)(ci * 32 + c) * 256 + ei * 16 + e0 + 8] = a1;
  }
}

// ---------------------------------------------------------------------------
// Main fused kernel: round-3 structure, re-partitioned onto 8 thin waves
// (512 threads).  Each wave owns 32 code/e-columns (j in {0,1}); per-wave
// register state halves -> more resident waves -> latency hidden by TLP.
// No manual register rotation (r4/r5 failed on that).
// ---------------------------------------------------------------------------
__global__ __launch_bounds__(512, 4) void main_kernel(
    const float* __restrict__ hidden, const int* __restrict__ mask,
    const float* __restrict__ gamma, const float* __restrict__ beta,
    const float* __restrict__ c2g, const float* __restrict__ code_out,
    const unsigned short* __restrict__ BT,
    float* __restrict__ loss_acc, unsigned* __restrict__ ticket,
    float* __restrict__ out) {

  __shared__ unsigned short HZ[64 * 264];   // H then Z (33792 B), stride 264
  __shared__ float    z2[64];
  __shared__ unsigned sminp[512];
  __shared__ int      ridx[64];

  const int t    = threadIdx.x;             // 0..511
  const int lane = t & 63;
  const int w    = t >> 6;                  // wave 0..7
  const int l15  = lane & 15;
  const int quad = lane >> 4;
  const int row0 = blockIdx.x * 64;

  // c2 for this wave's 2x32 code columns
  float ccp[2][2];
  #pragma unroll
  for (int p = 0; p < 2; p++)
    #pragma unroll
    for (int j = 0; j < 2; j++)
      ccp[p][j] = c2g[p * 256 + w * 32 + j * 16 + l15];

  // ---- stage H: contiguous global reads, b128 LDS writes ----
  {
    #pragma unroll
    for (int i = 0; i < 4; i++) {
      int flat = (t * 8) + i * 4096;        // float index in 64x256 tile
      int r = flat >> 8, c = flat & 255;
      const float* src = hidden + (size_t)row0 * 256 + flat;
      float4 x0 = *(const float4*)src, x1 = *(const float4*)(src + 4);
      *(bf16x8*)(HZ + r * 264 + c) = pack8(x0, x1);
    }
  }
  __syncthreads();   // H visible

  const f32x4 zf = {0.f, 0.f, 0.f, 0.f};
  f32x4 acc[4][2];
  #pragma unroll
  for (int i = 0; i < 4; i++)
    #pragma unroll
    for (int j = 0; j < 2; j++) acc[i][j] = zf;

  // b-frag address: BT + chunk*8192 + w*1024 + j*512 + quad*128 + l15*8
  // (matches prep's layout for code/col c = w*32 + j*16 + l15)
  const unsigned short* BTw = BT + w * 1024 + lane * 8;

  // ---------------- Phase 1: Z = H * W_in^T ----------------
  #pragma unroll 2
  for (int ks = 0; ks < 8; ks++) {
    const unsigned short* bp = BTw + ks * 8192;
    bf16x8 b0 = *(const bf16x8*)(bp);
    bf16x8 b1 = *(const bf16x8*)(bp + 512);
    bf16x8 a[4];
    #pragma unroll
    for (int i = 0; i < 4; i++)
      a[i] = *(const bf16x8*)(HZ + (i * 16 + l15) * 264 + ks * 32 + quad * 8);
    #pragma unroll
    for (int i = 0; i < 4; i++) {
      acc[i][0] = __builtin_amdgcn_mfma_f32_16x16x32_bf16(a[i], b0, acc[i][0], 0, 0, 0);
      acc[i][1] = __builtin_amdgcn_mfma_f32_16x16x32_bf16(a[i], b1, acc[i][1], 0, 0, 0);
    }
  }

  __syncthreads();   // all H reads done
  // Z epilogue: C/D layout row = quad*4+reg, col = lane&15
  #pragma unroll
  for (int i = 0; i < 4; i++)
    #pragma unroll
    for (int j = 0; j < 2; j++)
      #pragma unroll
      for (int r = 0; r < 4; r++)
        HZ[(i * 16 + quad * 4 + r) * 264 + (w * 32 + j * 16 + l15)] =
            f2bf(acc[i][j][r]);
  __syncthreads();   // Z visible

  { // |z|^2 per row from bf16 Z (consistent with scores)
    int zr = t >> 3, part = t & 7;
    float s = 0.f;
    const unsigned short* zp = HZ + zr * 264 + part * 32;
    #pragma unroll
    for (int c = 0; c < 32; c += 8) {
      bf16x8 v = *(const bf16x8*)(zp + c);
      #pragma unroll
      for (int e = 0; e < 8; e++) { float f = bf2f((unsigned short)v[e]); s += f * f; }
    }
    s += __shfl_xor(s, 1);
    s += __shfl_xor(s, 2);
    s += __shfl_xor(s, 4);
    if (part == 0) z2[zr] = s;
  }

  // ---------------- Phase 2: scores + packed argmin ----------------
  unsigned runp[16];
  #pragma unroll
  for (int r = 0; r < 16; r++) runp[r] = 0xFFFFFFFFu;

  #pragma unroll
  for (int pass = 0; pass < 2; pass++) {
    #pragma unroll
    for (int i = 0; i < 4; i++)
      #pragma unroll
      for (int j = 0; j < 2; j++) acc[i][j] = zf;

    #pragma unroll 2
    for (int ks = 0; ks < 8; ks++) {
      const unsigned short* bp = BTw + (8 + pass * 8 + ks) * 8192;
      bf16x8 b0 = *(const bf16x8*)(bp);
      bf16x8 b1 = *(const bf16x8*)(bp + 512);
      bf16x8 a[4];
      #pragma unroll
      for (int i = 0; i < 4; i++)
        a[i] = *(const bf16x8*)(HZ + (i * 16 + l15) * 264 + ks * 32 + quad * 8);
      #pragma unroll
      for (int i = 0; i < 4; i++) {
        acc[i][0] = __builtin_amdgcn_mfma_f32_16x16x32_bf16(a[i], b0, acc[i][0], 0, 0, 0);
        acc[i][1] = __builtin_amdgcn_mfma_f32_16x16x32_bf16(a[i], b1, acc[i][1], 0, 0, 0);
      }
    }
    // fold: m = c2 - 2 z.c ; pack sortable (dist | 9-bit code); min
    #pragma unroll
    for (int i = 0; i < 4; i++)
      #pragma unroll
      for (int j = 0; j < 2; j++) {
        int code = pass * 256 + w * 32 + j * 16 + l15;
        float cc = ccp[pass][j];
        #pragma unroll
        for (int r = 0; r < 4; r++) {
          float m = cc - 2.f * acc[i][j][r];
          unsigned bits = __float_as_uint(m);
          unsigned u = bits ^ (0x80000000u | (unsigned)((int)bits >> 31));
          unsigned p = (u & 0xFFFFFE00u) | (unsigned)code;
          int ri = i * 4 + r;
          runp[ri] = min(runp[ri], p);
        }
      }
  }

  // reduce across the 16 lanes of each quad group
  #pragma unroll
  for (int ri = 0; ri < 16; ri++) {
    unsigned v = runp[ri];
    v = min(v, (unsigned)__shfl_xor((int)v, 1));
    v = min(v, (unsigned)__shfl_xor((int)v, 2));
    v = min(v, (unsigned)__shfl_xor((int)v, 4));
    v = min(v, (unsigned)__shfl_xor((int)v, 8));
    if (l15 == 0) {
      int i = ri >> 2, r = ri & 3;
      sminp[w * 64 + (i * 16 + quad * 4 + r)] = v;
    }
  }
  __syncthreads();

  if (t < 64) { // merge 8 waves, finalize idx + dist, block loss + ticket
    int row = t;
    unsigned bv = sminp[row];
    #pragma unroll
    for (int ww = 1; ww < 8; ww++) bv = min(bv, sminp[ww * 64 + row]);
    ridx[row] = (int)(bv & 511u);
    unsigned u = bv & 0xFFFFFE00u;
    unsigned bits = (u & 0x80000000u) ? (u ^ 0x80000000u) : ~u;
    float dist = z2[row] + __uint_as_float(bits);
    #pragma unroll
    for (int m = 1; m < 64; m <<= 1) dist += __shfl_xor(dist, m);
    if (t == 0) {
      atomicAdd(loss_acc, dist);
      __threadfence();
      unsigned done = atomicAdd(ticket, 1u);
      if (done == gridDim.x - 1) {
        float total = atomicAdd(loss_acc, 0.f);
        out[16777216] = 1.25f * total * (1.f / 16777216.f);
      }
    }
  }
  __syncthreads();

  // ---- phase 3: h = hidden + mask*code_out[idx]; LayerNorm; store ----
  {
    float4 g4 = *(const float4*)(gamma + lane * 4);
    float4 b4 = *(const float4*)(beta + lane * 4);
    for (int rr = 0; rr < 8; rr++) {
      int row = w * 8 + rr;
      int gr  = row0 + row;
      float4 h = *(const float4*)(hidden + (size_t)gr * 256 + lane * 4);
      int code = ridx[row];
      float4 o = *(const float4*)(code_out + (size_t)code * 256 + lane * 4);
      float mf = mask[gr] ? 1.f : 0.f;
      h.x += mf * o.x; h.y += mf * o.y; h.z += mf * o.z; h.w += mf * o.w;
      float s  = h.x + h.y + h.z + h.w;
      float sq = h.x * h.x + h.y * h.y + h.z * h.z + h.w * h.w;
      #pragma unroll
      for (int m = 1; m < 64; m <<= 1) { s += __shfl_xor(s, m); sq += __shfl_xor(sq, m); }
      float mean = s * (1.f / 256.f);
      float var  = sq * (1.f / 256.f) - mean * mean;
      float rstd = rsqrtf(var + LN_EPS);
      float4 res;
      res.x = (h.x - mean) * rstd * g4.x + b4.x;
      res.y = (h.y - mean) * rstd * g4.y + b4.y;
      res.z = (h.z - mean) * rstd * g4.z + b4.z;
      res.w = (h.w - mean) * rstd * g4.w + b4.w;
      *(float4*)(out + (size_t)gr * 256 + lane * 4) = res;
    }
  }
}

extern "C" void kernel_launch(void* const* d_in, const int* in_sizes, int n_in,
                              void* d_out, int out_size, void* d_ws, size_t ws_size,
                              hipStream_t stream) {
  (void)in_sizes; (void)n_in; (void)out_size; (void)ws_size;
  const float* hidden   = (const float*)d_in[0];
  const int*   mask     = (const int*)d_in[1];
  const float* codebook = (const float*)d_in[2];
  const float* W_in     = (const float*)d_in[3];
  const float* W_out    = (const float*)d_in[4];
  const float* gamma    = (const float*)d_in[5];
  const float* beta     = (const float*)d_in[6];
  float* out = (float*)d_out;

  float* wsf      = (float*)d_ws;
  float* loss_acc = wsf;                        // [1]
  unsigned* ticket = (unsigned*)(wsf + 1);      // [1]
  float* c2       = wsf + 64;                   // [512]
  float* code_out = wsf + 64 + 512;             // [512*256]
  unsigned short* BT = (unsigned short*)(wsf + 64 + 512 + 512 * 256); // 24*8192 bf16

  prep_kernel<<<352, 256, 0, stream>>>(codebook, W_in, W_out, loss_acc, ticket,
                                       c2, code_out, BT);
  main_kernel<<<1024, 512, 0, stream>>>(hidden, mask, gamma, beta, c2, code_out,
                                        BT, loss_acc, ticket, out);
}